// Round 2
// baseline (15261.290 us; speedup 1.0000x reference)
//
#include <hip/hip_runtime.h>

// DKVMN fused forward, round 2.
// Kernel A (gates): e=sigmoid(We v+be), a=tanh(Wa v+ba) for all (b,t) -> fp16 in ws.
// Kernel B (recurrence): grid=B=256 blocks x 1024 threads (16 waves/CU).
//   Per pass of U=8 steps: stage q,e,a -> logits -> softmax -> stream state
//   (reg-double-buffered, r via LDS atomics) -> 3-layer MLP -> preds.
// State (B*N*DV fp32 = 128 MB) in ws; pass 0 reads Vmem directly.
// Fallback (<256 MB ws): gates computed in-loop by waves 8-15 during softmax.

#define B_ 256
#define T_ 512
#define N_ 512
#define DK_ 64
#define DV_ 256
#define S_ 64
#define U_ 8
#define NTB 1024
#define NPASS (T_ / U_)

typedef _Float16 half_t;

__device__ __forceinline__ float dot4(float4 a, float4 b) {
  return a.x * b.x + a.y * b.y + a.z * b.z + a.w * b.w;
}

// ---------------- Kernel A: gates precompute ----------------
__global__ __launch_bounds__(256, 4) void gates_kernel(
    const int* __restrict__ interactions, const float* __restrict__ iemb,
    const float* __restrict__ We, const float* __restrict__ be,
    const float* __restrict__ Wa, const float* __restrict__ ba,
    half_t* __restrict__ e_h, half_t* __restrict__ a_h) {
  __shared__ float s_v[32][DV_];
  __shared__ int s_id[32];
  const int tid = threadIdx.x;
  const int g = blockIdx.x;  // 32 (b,t) pairs per block, flat pair index
  if (tid < 32) s_id[tid] = interactions[g * 32 + tid];
  __syncthreads();
  const float4* iemb4 = (const float4*)iemb;
  for (int idx = tid; idx < 32 * (DV_ / 4); idx += 256) {
    const int p = idx >> 6, f = idx & 63;
    const int id = s_id[p];
    float4 v = id ? iemb4[id * (DV_ / 4) + f] : make_float4(0.f, 0.f, 0.f, 0.f);
    *(float4*)&s_v[p][f * 4] = v;
  }
  __syncthreads();
  const int d = tid;  // output dim, 256 threads
  float accE[32], accA[32];
#pragma unroll
  for (int p = 0; p < 32; ++p) { accE[p] = 0.f; accA[p] = 0.f; }
  const float4* We4 = (const float4*)(We + d * DV_);
  const float4* Wa4 = (const float4*)(Wa + d * DV_);
  for (int kk = 0; kk < DV_ / 4; ++kk) {
    const float4 we = We4[kk], wa = Wa4[kk];
#pragma unroll
    for (int p = 0; p < 32; ++p) {
      const float4 v = *(const float4*)&s_v[p][kk * 4];
      accE[p] += dot4(we, v);
      accA[p] += dot4(wa, v);
    }
  }
  const float bed = be[d], bad = ba[d];
  for (int p = 0; p < 32; ++p) {
    const size_t o = (size_t)(g * 32 + p) * DV_ + d;
    e_h[o] = (half_t)(1.f / (1.f + expf(-(accE[p] + bed))));
    a_h[o] = (half_t)tanhf(accA[p] + bad);
  }
}

// ---------------- Kernel B: recurrence ----------------
template <bool PRE>
__global__ __launch_bounds__(NTB, 1) void dkvmn_kernel(
    const int* __restrict__ concepts, const int* __restrict__ interactions,
    const float* __restrict__ Kmem, const float* __restrict__ Vmem,
    const float* __restrict__ cemb, const float* __restrict__ iemb,
    const float* __restrict__ We, const float* __restrict__ be,
    const float* __restrict__ Wa, const float* __restrict__ ba,
    const float* __restrict__ W1, const float* __restrict__ b1,
    const float* __restrict__ W2, const float* __restrict__ b2,
    const float* __restrict__ W3, const float* __restrict__ b3,
    const half_t* __restrict__ e_h, const half_t* __restrict__ a_h,
    float* __restrict__ out, float* __restrict__ state) {
  __shared__ float s_q[U_][DK_];
  __shared__ float s_w[U_][N_];
  __shared__ float s_e[U_][DV_];
  __shared__ float s_a[U_][DV_];
  __shared__ float s_r[U_][DV_];
  __shared__ float s_v[U_][DV_];  // used only by !PRE path
  __shared__ float s_h1[U_][S_];
  __shared__ float s_h2[U_][S_];

  const int tid = threadIdx.x;
  const int b = blockIdx.x;
  const int lane = tid & 63;
  const int wid = tid >> 6;  // 16 waves
  float4* stb4 = (float4*)state + (size_t)b * (N_ * DV_ / 4);

  for (int pass = 0; pass < NPASS; ++pass) {
    const int t0 = pass * U_;
    __syncthreads();  // protect LDS from previous pass readers

    // ---- stage ----
    if (tid < U_ * DK_) {  // 512 threads: q
      const int u = tid >> 6, l = tid & 63;
      const int c = concepts[b * T_ + t0 + u];
      s_q[u][l] = c ? cemb[c * DK_ + l] : 0.f;
    }
    if (PRE) {
      for (int i = tid; i < U_ * DV_; i += NTB) {
        const int u = i >> 8, d = i & (DV_ - 1);
        const size_t o = (size_t)(b * T_ + t0 + u) * DV_ + d;
        s_e[u][d] = (float)e_h[o];
        s_a[u][d] = (float)a_h[o];
        s_r[u][d] = 0.f;
      }
    } else {
      for (int i = tid; i < U_ * DV_; i += NTB) {
        const int u = i >> 8, d = i & (DV_ - 1);
        const int iv = interactions[b * T_ + t0 + u];
        s_v[u][d] = iv ? iemb[iv * DV_ + d] : 0.f;
        s_r[u][d] = 0.f;
      }
    }
    __syncthreads();

    // ---- logits: 1024 threads, n = tid&511, each does 4 u's ----
    {
      const int n = tid & (N_ - 1), ug = tid >> 9;  // ug in {0,1}
      const float4* kr = (const float4*)(Kmem + n * DK_);
      float a0 = 0.f, a1 = 0.f, a2 = 0.f, a3 = 0.f;
#pragma unroll
      for (int kk = 0; kk < DK_ / 4; ++kk) {
        const float4 k4 = kr[kk];
        a0 += dot4(k4, *(const float4*)&s_q[ug * 4 + 0][kk * 4]);
        a1 += dot4(k4, *(const float4*)&s_q[ug * 4 + 1][kk * 4]);
        a2 += dot4(k4, *(const float4*)&s_q[ug * 4 + 2][kk * 4]);
        a3 += dot4(k4, *(const float4*)&s_q[ug * 4 + 3][kk * 4]);
      }
      s_w[ug * 4 + 0][n] = a0;
      s_w[ug * 4 + 1][n] = a1;
      s_w[ug * 4 + 2][n] = a2;
      s_w[ug * 4 + 3][n] = a3;
    }
    __syncthreads();

    // ---- softmax (waves 0-7); gates in-loop on waves 8-15 if !PRE ----
    if (wid < U_) {
      const int u = wid;
      float mx = -1e30f;
      for (int n = lane; n < N_; n += 64) mx = fmaxf(mx, s_w[u][n]);
      for (int off = 32; off > 0; off >>= 1) mx = fmaxf(mx, __shfl_xor(mx, off, 64));
      float sum = 0.f;
      for (int n = lane; n < N_; n += 64) {
        const float ex = expf(s_w[u][n] - mx);
        s_w[u][n] = ex;
        sum += ex;
      }
      for (int off = 32; off > 0; off >>= 1) sum += __shfl_xor(sum, off, 64);
      const float inv = 1.f / sum;
      for (int n = lane; n < N_; n += 64) s_w[u][n] *= inv;
    } else if (!PRE) {
      const int t2 = tid - 512;
      const int d = t2 & (DV_ - 1), g = t2 >> 8, ub = g * 4;
      float ae[4] = {0, 0, 0, 0}, aa[4] = {0, 0, 0, 0};
      const float4* wer = (const float4*)(We + d * DV_);
      const float4* war = (const float4*)(Wa + d * DV_);
      for (int kk = 0; kk < DV_ / 4; ++kk) {
        const float4 wev = wer[kk], wav = war[kk];
#pragma unroll
        for (int uu = 0; uu < 4; ++uu) {
          const float4 vv = *(const float4*)&s_v[ub + uu][kk * 4];
          ae[uu] += dot4(wev, vv);
          aa[uu] += dot4(wav, vv);
        }
      }
      const float bed = be[d], bad = ba[d];
#pragma unroll
      for (int uu = 0; uu < 4; ++uu) {
        s_e[ub + uu][d] = 1.f / (1.f + expf(-(ae[uu] + bed)));
        s_a[ub + uu][d] = tanhf(aa[uu] + bad);
      }
    }
    __syncthreads();

    // ---- stream: 16 waves x 32 rows, reg-double-buffered ----
    {
      const int d4 = lane;
      float4 e_reg[U_], a_reg[U_], racc[U_];
#pragma unroll
      for (int u = 0; u < U_; ++u) {
        e_reg[u] = *(const float4*)&s_e[u][d4 * 4];
        a_reg[u] = *(const float4*)&s_a[u][d4 * 4];
        racc[u] = make_float4(0.f, 0.f, 0.f, 0.f);
      }
      const float4* src = pass ? (const float4*)stb4 : (const float4*)Vmem;
      float4* dst = stb4;
      const int n0 = wid * 32;
      float4 mA = src[(n0 + 0) * (DV_ / 4) + d4];
      float4 mB = src[(n0 + 1) * (DV_ / 4) + d4];
      for (int c = 0; c < 32; c += 2) {
        float4 nxA, nxB;
        const bool more = (c + 2) < 32;
        if (more) {  // prefetch before the stores so loads stay in flight
          nxA = src[(n0 + c + 2) * (DV_ / 4) + d4];
          nxB = src[(n0 + c + 3) * (DV_ / 4) + d4];
        }
        const int na = n0 + c, nb = n0 + c + 1;
#pragma unroll
        for (int u = 0; u < U_; ++u) {
          const float w0 = s_w[u][na], w1 = s_w[u][nb];
          racc[u].x = fmaf(w0, mA.x, racc[u].x);
          racc[u].y = fmaf(w0, mA.y, racc[u].y);
          racc[u].z = fmaf(w0, mA.z, racc[u].z);
          racc[u].w = fmaf(w0, mA.w, racc[u].w);
          mA.x = fmaf(-w0, fmaf(e_reg[u].x, mA.x, -a_reg[u].x), mA.x);
          mA.y = fmaf(-w0, fmaf(e_reg[u].y, mA.y, -a_reg[u].y), mA.y);
          mA.z = fmaf(-w0, fmaf(e_reg[u].z, mA.z, -a_reg[u].z), mA.z);
          mA.w = fmaf(-w0, fmaf(e_reg[u].w, mA.w, -a_reg[u].w), mA.w);
          racc[u].x = fmaf(w1, mB.x, racc[u].x);
          racc[u].y = fmaf(w1, mB.y, racc[u].y);
          racc[u].z = fmaf(w1, mB.z, racc[u].z);
          racc[u].w = fmaf(w1, mB.w, racc[u].w);
          mB.x = fmaf(-w1, fmaf(e_reg[u].x, mB.x, -a_reg[u].x), mB.x);
          mB.y = fmaf(-w1, fmaf(e_reg[u].y, mB.y, -a_reg[u].y), mB.y);
          mB.z = fmaf(-w1, fmaf(e_reg[u].z, mB.z, -a_reg[u].z), mB.z);
          mB.w = fmaf(-w1, fmaf(e_reg[u].w, mB.w, -a_reg[u].w), mB.w);
        }
        dst[na * (DV_ / 4) + d4] = mA;
        dst[nb * (DV_ / 4) + d4] = mB;
        if (more) { mA = nxA; mB = nxB; }
      }
#pragma unroll
      for (int u = 0; u < U_; ++u) {
        atomicAdd(&s_r[u][d4 * 4 + 0], racc[u].x);
        atomicAdd(&s_r[u][d4 * 4 + 1], racc[u].y);
        atomicAdd(&s_r[u][d4 * 4 + 2], racc[u].z);
        atomicAdd(&s_r[u][d4 * 4 + 3], racc[u].w);
      }
    }
    __syncthreads();

    // ---- MLP (waves 0-7, u = wid) ----
    if (tid < 512) {
      const int u = wid;
      float acc = b1[lane];
      const float4* w1r = (const float4*)(W1 + lane * (DV_ + DK_));
#pragma unroll
      for (int kk = 0; kk < DV_ / 4; ++kk)
        acc += dot4(w1r[kk], *(const float4*)&s_r[u][kk * 4]);
#pragma unroll
      for (int kk = 0; kk < DK_ / 4; ++kk)
        acc += dot4(w1r[DV_ / 4 + kk], *(const float4*)&s_q[u][kk * 4]);
      s_h1[u][lane] = fmaxf(acc, 0.f);
    }
    __syncthreads();
    if (tid < 512) {
      const int u = wid;
      float acc = b2[lane];
      const float4* w2r = (const float4*)(W2 + lane * S_);
#pragma unroll
      for (int kk = 0; kk < S_ / 4; ++kk)
        acc += dot4(w2r[kk], *(const float4*)&s_h1[u][kk * 4]);
      s_h2[u][lane] = fmaxf(acc, 0.f);
    }
    __syncthreads();
    if (tid < 512) {
      const int u = wid;
      float p = s_h2[u][lane] * W3[lane];
      for (int off = 32; off > 0; off >>= 1) p += __shfl_xor(p, off, 64);
      if (lane == 0)
        out[(size_t)b * T_ + t0 + u] = 1.f / (1.f + expf(-(p + b3[0])));
    }
  }
}

extern "C" void kernel_launch(void* const* d_in, const int* in_sizes, int n_in,
                              void* d_out, int out_size, void* d_ws, size_t ws_size,
                              hipStream_t stream) {
  const int* concepts = (const int*)d_in[0];
  const int* interactions = (const int*)d_in[1];
  const float* Kmem = (const float*)d_in[2];
  const float* Vmem = (const float*)d_in[3];
  const float* cemb = (const float*)d_in[4];
  const float* iemb = (const float*)d_in[5];
  const float* We = (const float*)d_in[6];
  const float* be = (const float*)d_in[7];
  const float* Wa = (const float*)d_in[8];
  const float* ba = (const float*)d_in[9];
  const float* W1 = (const float*)d_in[10];
  const float* b1 = (const float*)d_in[11];
  const float* W2 = (const float*)d_in[12];
  const float* b2 = (const float*)d_in[13];
  const float* W3 = (const float*)d_in[14];
  const float* b3 = (const float*)d_in[15];
  float* out = (float*)d_out;

  const size_t state_bytes = (size_t)B_ * N_ * DV_ * 4;      // 128 MB
  const size_t ea_bytes = (size_t)B_ * T_ * DV_ * 2;         // 64 MB each
  float* state = (float*)d_ws;
  half_t* e_h = (half_t*)((char*)d_ws + state_bytes);
  half_t* a_h = (half_t*)((char*)d_ws + state_bytes + ea_bytes);

  if (ws_size >= state_bytes + 2 * ea_bytes) {
    gates_kernel<<<dim3(B_ * T_ / 32), dim3(256), 0, stream>>>(
        interactions, iemb, We, be, Wa, ba, e_h, a_h);
    dkvmn_kernel<true><<<dim3(B_), dim3(NTB), 0, stream>>>(
        concepts, interactions, Kmem, Vmem, cemb, iemb, We, be, Wa, ba,
        W1, b1, W2, b2, W3, b3, e_h, a_h, out, state);
  } else {
    dkvmn_kernel<false><<<dim3(B_), dim3(NTB), 0, stream>>>(
        concepts, interactions, Kmem, Vmem, cemb, iemb, We, be, Wa, ba,
        W1, b1, W2, b2, W3, b3, e_h, a_h, out, state);
  }
}